// Round 1
// baseline (950.427 us; speedup 1.0000x reference)
//
#include <hip/hip_runtime.h>
#include <hip/hip_bf16.h>

#define CHW 65536   // 16 ch * 64 * 64 per bg-group

__device__ __forceinline__ float wred(float v){
#pragma unroll
  for (int o = 32; o; o >>= 1) v += __shfl_xor(v, o, 64);
  return v;
}

// ---------------- K1: pooled means -> 1x1 convs -> a_h, a_w ----------------
__global__ __launch_bounds__(256) void k1_attn(const float* __restrict__ x,
    const float* __restrict__ w1, const float* __restrict__ b1,
    const float* __restrict__ wh, const float* __restrict__ bh,
    const float* __restrict__ ww, const float* __restrict__ bw,
    float* __restrict__ aH, float* __restrict__ aW)
{
  __shared__ float rs[1024];      // rowsum[cg*64+h]
  __shared__ float cs[1024];      // colsum[cg*64+w]
  __shared__ float ym[16*128];    // y
  int tid = threadIdx.x;
  int bg  = blockIdx.x;
  size_t base = (size_t)bg * CHW;
  for (int i = tid; i < 1024; i += 256) cs[i] = 0.f;
  __syncthreads();
  int lane = tid & 63, wv = tid >> 6;
  float colacc = 0.f;
  for (int k = 0; k < 256; ++k){
    int idx = k*256 + tid;
    float val = x[base + idx];
    float rsum = wred(val);
    int r = k*4 + wv;             // r = cg*64 + h, each row exactly once
    if (lane == 0) rs[r] = rsum;
    colacc += val;
    if ((k & 15) == 15){
      int cg = k >> 4;
      atomicAdd(&cs[cg*64 + lane], colacc);
      colacc = 0.f;
    }
  }
  __syncthreads();
  // y = relu(w1 @ [rowmean|colmean] + b1)
  for (int ol = tid; ol < 2048; ol += 256){
    int o = ol >> 7, l = ol & 127;
    float acc = b1[o];
#pragma unroll
    for (int i = 0; i < 16; ++i){
      float mv = (l < 64 ? rs[i*64 + l] : cs[i*64 + (l-64)]) * (1.f/64.f);
      acc = fmaf(w1[o*16 + i], mv, acc);
    }
    ym[o*128 + l] = fmaxf(acc, 0.f);
  }
  __syncthreads();
  for (int ol = tid; ol < 2048; ol += 256){
    int q = ol >> 10;             // 0 -> a_h, 1 -> a_w
    int o = (ol >> 6) & 15;
    int p = ol & 63;
    const float* Wm = q ? ww : wh;
    float acc = q ? bw[o] : bh[o];
#pragma unroll
    for (int i = 0; i < 16; ++i)
      acc = fmaf(Wm[o*16 + i], ym[i*128 + q*64 + p], acc);
    float sg = 1.f / (1.f + __expf(-acc));
    (q ? aW : aH)[((size_t)bg*16 + o)*64 + p] = sg;
  }
}

// ---------------- K2: mu/var, V2, Z2 ----------------
__global__ __launch_bounds__(256) void k2_stats(const float* __restrict__ x,
    const float* __restrict__ aH, const float* __restrict__ aW,
    const float* __restrict__ gnw, const float* __restrict__ gnb,
    float* __restrict__ MU, float* __restrict__ RSTD,
    float* __restrict__ V2, float* __restrict__ Z2)
{
  __shared__ float ahs[1024], aws[1024];
  __shared__ float chans[16], z2s[16];
  __shared__ float red_s[8];
  __shared__ float murs[2];
  __shared__ float sc_s[16], of_s[16];
  int tid = threadIdx.x; int bg = blockIdx.x;
  size_t base = (size_t)bg * CHW;
  for (int i = tid; i < 1024; i += 256){
    ahs[i] = aH[(size_t)bg*1024 + i];
    aws[i] = aW[(size_t)bg*1024 + i];
  }
  if (tid < 16){ chans[tid] = 0.f; z2s[tid] = 0.f; }
  __syncthreads();
  int lane = tid & 63, wv = tid >> 6;
  float s1 = 0.f, s2 = 0.f, cacc = 0.f;
  for (int k = 0; k < 256; ++k){
    int idx = k*256 + tid;
    int cg = k >> 4;
    int h = (k*4 + wv) & 63;
    float val = x[base + idx];
    float x1 = val * ahs[cg*64 + h] * aws[cg*64 + lane];
    s1 += x1; s2 = fmaf(x1, x1, s2); cacc += x1;
    if ((k & 15) == 15){
      float rsum = wred(cacc);
      if (lane == 0) atomicAdd(&chans[cg], rsum);
      cacc = 0.f;
    }
  }
  float r1 = wred(s1), r2 = wred(s2);
  if (lane == 0){ red_s[wv] = r1; red_s[4+wv] = r2; }
  __syncthreads();
  if (tid == 0){
    float S  = red_s[0]+red_s[1]+red_s[2]+red_s[3];
    float SS = red_s[4]+red_s[5]+red_s[6]+red_s[7];
    float mu = S * (1.f/65536.f);
    float var = SS * (1.f/65536.f) - mu*mu;
    float rstd = rsqrtf(var + 1e-5f);
    murs[0] = mu; murs[1] = rstd;
    MU[bg] = mu; RSTD[bg] = rstd;
  }
  __syncthreads();
  float mu = murs[0], rstd = murs[1];
  if (tid < 16){
    float g = gnw[tid], b = gnb[tid];
    float sc = rstd * g;
    sc_s[tid] = sc; of_s[tid] = b - mu*sc;
    V2[(size_t)bg*16 + tid] = (chans[tid] * (1.f/4096.f) - mu) * sc + b;
  }
  __syncthreads();
  float zacc = 0.f;
  for (int k = 0; k < 256; ++k){
    int idx = k*256 + tid;
    int cg = k >> 4;
    int h = (k*4 + wv) & 63;
    float val = x[base + idx];
    float x1 = val * ahs[cg*64 + h] * aws[cg*64 + lane];
    float x2 = fmaf(x1, sc_s[cg], of_s[cg]);
    zacc += __expf(x2);
    if ((k & 15) == 15){
      float rsum = wred(zacc);
      if (lane == 0) atomicAdd(&z2s[cg], rsum);
      zacc = 0.f;
    }
  }
  __syncthreads();
  if (tid < 16) Z2[(size_t)bg*16 + tid] = z2s[tid];
}

// ---------------- K3: 3x3 grouped conv -> x3 (bf16), V3, Z3 ----------------
__global__ __launch_bounds__(256) void k3_conv(const float* __restrict__ x,
    const float* __restrict__ w3, const float* __restrict__ b3,
    __hip_bfloat16* __restrict__ X3, float* __restrict__ V3, float* __restrict__ Z3)
{
  __shared__ __align__(16) float in_s[16*10*76];  // 47.5 KB
  int tid = threadIdx.x; int bg = blockIdx.x;
  size_t base = (size_t)bg * CHW;
  int lane = tid & 63;
  int cog = __builtin_amdgcn_readfirstlane(tid >> 6);  // wave-uniform co group
  int co0 = cog * 4;
  int p = tid & 63;
  int r  = p >> 3;          // 0..7 output row within stripe
  int w0 = (p & 7) * 8;     // 8 consecutive output cols
  float bias[4], v3acc[4] = {0,0,0,0}, z3acc[4] = {0,0,0,0};
#pragma unroll
  for (int i = 0; i < 4; ++i) bias[i] = b3[co0+i];
#pragma unroll 1
  for (int s = 0; s < 8; ++s){
    __syncthreads();
    for (int idx = tid; idx < 12160; idx += 256){
      int j  = idx % 76;
      int rr = (idx / 76) % 10;
      int ci = idx / 760;
      int wc = j - 4;
      int h  = s*8 - 1 + rr;
      float val = 0.f;
      if ((unsigned)wc < 64u && (unsigned)h < 64u)
        val = x[base + ci*4096 + h*64 + wc];
      in_s[(ci*10 + rr)*76 + j] = val;
    }
    __syncthreads();
    float acc[4][8];
#pragma unroll
    for (int i = 0; i < 4; ++i)
#pragma unroll
      for (int px = 0; px < 8; ++px) acc[i][px] = 0.f;
#pragma unroll 1
    for (int ci = 0; ci < 16; ++ci){
      float wgt[4][9];
#pragma unroll
      for (int i = 0; i < 4; ++i)
#pragma unroll
        for (int t = 0; t < 9; ++t)
          wgt[i][t] = w3[((co0+i)*16 + ci)*9 + t];   // scalar loads (co0 uniform)
#pragma unroll
      for (int dy = 0; dy < 3; ++dy){
        const float* row = &in_s[(ci*10 + r + dy)*76 + w0];
        float4 A0 = *(const float4*)(row);
        float4 A1 = *(const float4*)(row+4);
        float4 A2v = *(const float4*)(row+8);
        float4 A3v = *(const float4*)(row+12);
        float v[16] = {A0.x,A0.y,A0.z,A0.w, A1.x,A1.y,A1.z,A1.w,
                       A2v.x,A2v.y,A2v.z,A2v.w, A3v.x,A3v.y,A3v.z,A3v.w};
#pragma unroll
        for (int dx = 0; dx < 3; ++dx){
#pragma unroll
          for (int px = 0; px < 8; ++px){
            float iv = v[px + dx + 3];   // input col w0+px+dx-1 -> j-w0 = px+dx+3
#pragma unroll
            for (int i = 0; i < 4; ++i)
              acc[i][px] = fmaf(wgt[i][dy*3+dx], iv, acc[i][px]);
          }
        }
      }
    }
    int h = s*8 + r;
#pragma unroll
    for (int i = 0; i < 4; ++i){
      union { __hip_bfloat16 hb[8]; uint4 u; } pk;
#pragma unroll
      for (int px = 0; px < 8; ++px){
        float val = fmaxf(acc[i][px] + bias[i], 0.f);
        __hip_bfloat16 hv = __float2bfloat16(val);
        float vq = __bfloat162float(hv);     // use rounded value for stats (consistency)
        v3acc[i] += vq;
        z3acc[i] += __expf(vq);
        pk.hb[px] = hv;
      }
      *(uint4*)&X3[base + (size_t)(co0+i)*4096 + h*64 + w0] = pk.u;
    }
  }
#pragma unroll
  for (int i = 0; i < 4; ++i){
    float rv = wred(v3acc[i]);
    float rz = wred(z3acc[i]);
    if (lane == 0){
      V3[(size_t)bg*16 + co0 + i] = rv * (1.f/4096.f);
      Z3[(size_t)bg*16 + co0 + i] = rz;
    }
  }
}

// ---------------- K4: t = V2*A3 + V3*A2, softmax over l, out = x*s ----------------
__global__ __launch_bounds__(256) void k4_final(const float* __restrict__ x,
    const __hip_bfloat16* __restrict__ X3,
    const float* __restrict__ aH, const float* __restrict__ aW,
    const float* __restrict__ gnw, const float* __restrict__ gnb,
    const float* __restrict__ MU, const float* __restrict__ RSTD,
    const float* __restrict__ V2, const float* __restrict__ Z2,
    const float* __restrict__ V3, const float* __restrict__ Z3,
    float* __restrict__ out)
{
  __shared__ float t[4096];
  __shared__ float ahs[1024], aws[1024];
  __shared__ float sc_s[16], of_s[16], p2s[16], p3s[16];
  __shared__ float red_s[8];
  __shared__ float invS_s;
  int tid = threadIdx.x; int bg = blockIdx.x;
  size_t base = (size_t)bg * CHW;
  for (int i = tid; i < 1024; i += 256){
    ahs[i] = aH[(size_t)bg*1024 + i];
    aws[i] = aW[(size_t)bg*1024 + i];
  }
  for (int i = tid; i < 4096; i += 256) t[i] = 0.f;
  if (tid < 16){
    float mu = MU[bg], rstd = RSTD[bg];
    float g = gnw[tid], b = gnb[tid];
    float sc = rstd*g;
    sc_s[tid] = sc; of_s[tid] = b - mu*sc;
    p2s[tid] = V3[(size_t)bg*16+tid] / Z2[(size_t)bg*16+tid];
    p3s[tid] = V2[(size_t)bg*16+tid] / Z3[(size_t)bg*16+tid];
  }
  __syncthreads();
  int lane = tid & 63, wv = tid >> 6;
  for (int k = 0; k < 256; ++k){
    int idx = k*256 + tid;
    int cg = k >> 4;
    int h = (k*4 + wv) & 63;
    int l = idx & 4095;
    float val = x[base + idx];
    float x1 = val * ahs[cg*64 + h] * aws[cg*64 + lane];
    float x2 = fmaf(x1, sc_s[cg], of_s[cg]);
    float e2 = __expf(x2) * p2s[cg];
    float x3v = __bfloat162float(X3[base + idx]);
    float e3 = __expf(x3v) * p3s[cg];
    atomicAdd(&t[l], e2 + e3);
  }
  __syncthreads();
  float sacc = 0.f;
  for (int i = tid; i < 4096; i += 256){
    float e = __expf(t[i]);
    t[i] = e;
    sacc += e;
  }
  float rsum = wred(sacc);
  if (lane == 0) red_s[wv] = rsum;
  __syncthreads();
  if (tid == 0) invS_s = 1.f / (red_s[0]+red_s[1]+red_s[2]+red_s[3]);
  __syncthreads();
  float invS = invS_s;
  for (int k = 0; k < 256; ++k){
    int idx = k*256 + tid;
    out[base + idx] = x[base + idx] * t[idx & 4095] * invS;
  }
}

extern "C" void kernel_launch(void* const* d_in, const int* in_sizes, int n_in,
                              void* d_out, int out_size, void* d_ws, size_t ws_size,
                              hipStream_t stream)
{
  const float* x   = (const float*)d_in[0];
  const float* w1  = (const float*)d_in[1];
  const float* b1  = (const float*)d_in[2];
  const float* wh  = (const float*)d_in[3];
  const float* bh  = (const float*)d_in[4];
  const float* ww  = (const float*)d_in[5];
  const float* bw  = (const float*)d_in[6];
  const float* w3  = (const float*)d_in[7];
  const float* b3  = (const float*)d_in[8];
  const float* gnw = (const float*)d_in[9];
  const float* gnb = (const float*)d_in[10];
  float* out = (float*)d_out;

  float* Wp   = (float*)d_ws;
  float* aH   = Wp;                 // 512*16*64
  float* aW_  = aH + 524288;        // 512*16*64
  float* MU   = aW_ + 524288;       // 512
  float* RSTD = MU + 512;           // 512
  float* V2   = RSTD + 512;         // 8192
  float* Z2   = V2 + 8192;          // 8192
  float* V3   = Z2 + 8192;          // 8192
  float* Z3   = V3 + 8192;          // 8192
  __hip_bfloat16* X3 = (__hip_bfloat16*)(Z3 + 8192);  // 33554432 bf16 (64 MB)
  (void)ws_size; (void)n_in; (void)in_sizes; (void)out_size;

  k1_attn <<<512, 256, 0, stream>>>(x, w1, b1, wh, bh, ww, bw, aH, aW_);
  k3_conv <<<512, 256, 0, stream>>>(x, w3, b3, X3, V3, Z3);
  k2_stats<<<512, 256, 0, stream>>>(x, aH, aW_, gnw, gnb, MU, RSTD, V2, Z2);
  k4_final<<<512, 256, 0, stream>>>(x, X3, aH, aW_, gnw, gnb, MU, RSTD, V2, Z2, V3, Z3, out);
}

// Round 2
// 512.600 us; speedup vs baseline: 1.8541x; 1.8541x over previous
//
#include <hip/hip_runtime.h>
#include <hip/hip_bf16.h>

#define CHW  65536   // 16 ch * 64 * 64 per bg-group
#define CHW4 16384   // in float4

__device__ __forceinline__ float wred(float v){
#pragma unroll
  for (int o = 32; o; o >>= 1) v += __shfl_xor(v, o, 64);
  return v;
}
__device__ __forceinline__ float wred16(float v){
#pragma unroll
  for (int o = 8; o; o >>= 1) v += __shfl_xor(v, o, 64);
  return v;
}
__device__ __forceinline__ float bf2f(unsigned short u){
  return __uint_as_float(((unsigned)u) << 16);
}

// ---------------- K1: pooled sums -> 1x1 convs -> a_h, a_w ----------------
__global__ __launch_bounds__(1024) void k1_attn(const float* __restrict__ x,
    const float* __restrict__ w1, const float* __restrict__ b1,
    const float* __restrict__ wh, const float* __restrict__ bh,
    const float* __restrict__ ww, const float* __restrict__ bw,
    float* __restrict__ aH, float* __restrict__ aW)
{
  __shared__ float rs[1024];      // rowsum[ch*64+h]
  __shared__ float cs[1024];      // colsum[ch*64+w]
  __shared__ float ym[2048];
  int tid = threadIdx.x, bg = blockIdx.x;
  const float4* x4 = (const float4*)x + (size_t)bg * CHW4;
  cs[tid] = 0.f;
  __syncthreads();
  int h = tid >> 4, lane = tid & 63;
#pragma unroll 4
  for (int k = 0; k < 16; ++k){          // k == channel
    float4 v = x4[k*1024 + tid];
    float s = v.x + v.y + v.z + v.w;
    s = wred16(s);
    if ((tid & 15) == 0) rs[k*64 + h] = s;
    // column partials: reduce over the wave's 4 h values (lanes l, l^16, l^32, l^48)
    v.x += __shfl_xor(v.x, 16); v.x += __shfl_xor(v.x, 32);
    v.y += __shfl_xor(v.y, 16); v.y += __shfl_xor(v.y, 32);
    v.z += __shfl_xor(v.z, 16); v.z += __shfl_xor(v.z, 32);
    v.w += __shfl_xor(v.w, 16); v.w += __shfl_xor(v.w, 32);
    if (lane < 16){
      atomicAdd(&cs[k*64 + lane*4 + 0], v.x);
      atomicAdd(&cs[k*64 + lane*4 + 1], v.y);
      atomicAdd(&cs[k*64 + lane*4 + 2], v.z);
      atomicAdd(&cs[k*64 + lane*4 + 3], v.w);
    }
  }
  __syncthreads();
  // y = relu(w1 @ [rowmean|colmean] + b1)
  for (int ol = tid; ol < 2048; ol += 1024){
    int o = ol >> 7, l = ol & 127;
    float acc = b1[o];
#pragma unroll
    for (int i = 0; i < 16; ++i){
      float mv = (l < 64 ? rs[i*64 + l] : cs[i*64 + (l-64)]) * (1.f/64.f);
      acc = fmaf(w1[o*16 + i], mv, acc);
    }
    ym[o*128 + l] = fmaxf(acc, 0.f);
  }
  __syncthreads();
  for (int ol = tid; ol < 2048; ol += 1024){
    int q = ol >> 10;             // 0 -> a_h, 1 -> a_w
    int o = (ol >> 6) & 15;
    int p = ol & 63;
    const float* Wm = q ? ww : wh;
    float acc = q ? bw[o] : bh[o];
#pragma unroll
    for (int i = 0; i < 16; ++i)
      acc = fmaf(Wm[o*16 + i], ym[i*128 + q*64 + p], acc);
    float sg = 1.f / (1.f + __expf(-acc));
    (q ? aW : aH)[((size_t)bg*16 + o)*64 + p] = sg;
  }
}

// ---------------- K2: mu/var, V2, Z2 ----------------
__global__ __launch_bounds__(1024) void k2_stats(const float* __restrict__ x,
    const float* __restrict__ aH, const float* __restrict__ aW,
    const float* __restrict__ gnw, const float* __restrict__ gnb,
    float* __restrict__ MU, float* __restrict__ RSTD,
    float* __restrict__ V2, float* __restrict__ Z2)
{
  __shared__ __align__(16) float ahs[1024], aws[1024];
  __shared__ float chpart[256], zpart[256];
  __shared__ float red1[16], red2[16];
  __shared__ float murs[2], sc_s[16], of_s[16];
  int tid = threadIdx.x, bg = blockIdx.x;
  const float4* x4 = (const float4*)x + (size_t)bg * CHW4;
  ahs[tid] = aH[(size_t)bg*1024 + tid];
  aws[tid] = aW[(size_t)bg*1024 + tid];
  __syncthreads();
  int h = tid >> 4, w4 = tid & 15, lane = tid & 63, wv = tid >> 6;
  const float4* aws4 = (const float4*)aws;
  float s1 = 0.f, s2 = 0.f;
#pragma unroll 4
  for (int k = 0; k < 16; ++k){
    float4 v = x4[k*1024 + tid];
    float ah = ahs[k*64 + h];
    float4 aw = aws4[k*16 + w4];
    float4 x1;
    x1.x = v.x * ah * aw.x;
    x1.y = v.y * ah * aw.y;
    x1.z = v.z * ah * aw.z;
    x1.w = v.w * ah * aw.w;
    float csum = x1.x + x1.y + x1.z + x1.w;
    s1 += csum;
    s2 = fmaf(x1.x, x1.x, s2); s2 = fmaf(x1.y, x1.y, s2);
    s2 = fmaf(x1.z, x1.z, s2); s2 = fmaf(x1.w, x1.w, s2);
    float cw = wred(csum);
    if (lane == 0) chpart[k*16 + wv] = cw;
  }
  float r1 = wred(s1), r2 = wred(s2);
  if (lane == 0){ red1[wv] = r1; red2[wv] = r2; }
  __syncthreads();
  if (tid == 0){
    float S = 0.f, SS = 0.f;
#pragma unroll
    for (int i = 0; i < 16; ++i){ S += red1[i]; SS += red2[i]; }
    float mu = S * (1.f/65536.f);
    float var = SS * (1.f/65536.f) - mu*mu;
    float rstd = rsqrtf(var + 1e-5f);
    murs[0] = mu; murs[1] = rstd;
    MU[bg] = mu; RSTD[bg] = rstd;
  }
  __syncthreads();
  if (tid < 16){
    float ch = 0.f;
#pragma unroll
    for (int m = 0; m < 16; ++m) ch += chpart[tid*16 + m];
    float mu = murs[0], rstd = murs[1];
    float g = gnw[tid], b = gnb[tid];
    float sc = rstd * g;
    sc_s[tid] = sc; of_s[tid] = b - mu*sc;
    V2[(size_t)bg*16 + tid] = (ch * (1.f/4096.f) - mu) * sc + b;
  }
  __syncthreads();
#pragma unroll 2
  for (int k = 0; k < 16; ++k){
    float4 v = x4[k*1024 + tid];
    float ah = ahs[k*64 + h];
    float4 aw = aws4[k*16 + w4];
    float sc = sc_s[k], of = of_s[k];
    float z =  __expf(fmaf(v.x * ah * aw.x, sc, of));
    z += __expf(fmaf(v.y * ah * aw.y, sc, of));
    z += __expf(fmaf(v.z * ah * aw.z, sc, of));
    z += __expf(fmaf(v.w * ah * aw.w, sc, of));
    float zw = wred(z);
    if (lane == 0) zpart[k*16 + wv] = zw;
  }
  __syncthreads();
  if (tid < 16){
    float z = 0.f;
#pragma unroll
    for (int m = 0; m < 16; ++m) z += zpart[tid*16 + m];
    Z2[(size_t)bg*16 + tid] = z;
  }
}

// ---------------- K3: 3x3 grouped conv -> x3 (bf16), V3/Z3 raw sums ----------------
#define STR 84     // padded LDS row stride (floats)
__global__ __launch_bounds__(256, 3) void k3_conv(const float* __restrict__ x,
    const float* __restrict__ w3, const float* __restrict__ b3,
    __hip_bfloat16* __restrict__ X3, float* __restrict__ V3, float* __restrict__ Z3)
{
  __shared__ __align__(16) float in_s[16*10*STR];  // 52.5 KB -> 3 blocks/CU
  int tid = threadIdx.x;
  int s   = blockIdx.x;      // stripe 0..7
  int bg  = blockIdx.y;
  size_t base  = (size_t)bg * CHW;
  const float4* x4 = (const float4*)x + (size_t)bg * CHW4;
  int lane = tid & 63;
  int cog = __builtin_amdgcn_readfirstlane(tid >> 6);
  int co0 = cog * 4;
  int r  = lane >> 3;          // 0..7 output row within stripe
  int w0 = (lane & 7) * 8;     // 8 consecutive output cols
  // ---- stage 16ci x 10 rows x 72 cols (cols -4..67, zero-padded) ----
  for (int idx = tid; idx < 2880; idx += 256){
    int q  = idx % 18;           // float4 column chunk
    int rr = (idx / 18) % 10;
    int ci = idx / 180;
    int hh = s*8 - 1 + rr;
    float4 v = make_float4(0.f, 0.f, 0.f, 0.f);
    if (q >= 1 && q <= 16 && (unsigned)hh < 64u)
      v = x4[ci*1024 + hh*16 + (q-1)];
    *(float4*)&in_s[(ci*10 + rr)*STR + q*4] = v;
  }
  float bias[4];
#pragma unroll
  for (int i = 0; i < 4; ++i) bias[i] = b3[co0+i];
  float acc[4][8];
#pragma unroll
  for (int i = 0; i < 4; ++i)
#pragma unroll
    for (int px = 0; px < 8; ++px) acc[i][px] = 0.f;
  __syncthreads();
#pragma unroll 1
  for (int ci = 0; ci < 16; ++ci){
    float wgt[4][9];
#pragma unroll
    for (int i = 0; i < 4; ++i)
#pragma unroll
      for (int t = 0; t < 9; ++t)
        wgt[i][t] = w3[((co0+i)*16 + ci)*9 + t];   // wave-uniform -> scalar loads
#pragma unroll
    for (int dy = 0; dy < 3; ++dy){
      const float* row = &in_s[(ci*10 + r + dy)*STR + w0];
      float4 A0 = *(const float4*)(row);
      float4 A1 = *(const float4*)(row+4);
      float4 A2v = *(const float4*)(row+8);
      float4 A3v = *(const float4*)(row+12);
      float v[16] = {A0.x,A0.y,A0.z,A0.w, A1.x,A1.y,A1.z,A1.w,
                     A2v.x,A2v.y,A2v.z,A2v.w, A3v.x,A3v.y,A3v.z,A3v.w};
#pragma unroll
      for (int dx = 0; dx < 3; ++dx){
#pragma unroll
        for (int px = 0; px < 8; ++px){
          float iv = v[px + dx + 3];
#pragma unroll
          for (int i = 0; i < 4; ++i)
            acc[i][px] = fmaf(wgt[i][dy*3+dx], iv, acc[i][px]);
        }
      }
    }
  }
  int hh = s*8 + r;
  float v3acc[4], z3acc[4];
#pragma unroll
  for (int i = 0; i < 4; ++i){
    union { __hip_bfloat16 hb[8]; uint4 u; } pk;
    v3acc[i] = 0.f; z3acc[i] = 0.f;
#pragma unroll
    for (int px = 0; px < 8; ++px){
      float val = fmaxf(acc[i][px] + bias[i], 0.f);
      __hip_bfloat16 hv = __float2bfloat16(val);
      float vq = __bfloat162float(hv);
      v3acc[i] += vq;
      z3acc[i] += __expf(vq);
      pk.hb[px] = hv;
    }
    *(uint4*)&X3[base + (size_t)(co0+i)*4096 + hh*64 + w0] = pk.u;
  }
#pragma unroll
  for (int i = 0; i < 4; ++i){
    float rv = wred(v3acc[i]);
    float rz = wred(z3acc[i]);
    if (lane == 0){
      atomicAdd(&V3[(size_t)bg*16 + co0 + i], rv);   // raw sum (scaled in k4)
      atomicAdd(&Z3[(size_t)bg*16 + co0 + i], rz);
    }
  }
}

// ---------------- K4: t = V2*A3 + V3*A2 (register-private), softmax, out ----------------
__global__ __launch_bounds__(1024) void k4_final(const float* __restrict__ x,
    const __hip_bfloat16* __restrict__ X3,
    const float* __restrict__ aH, const float* __restrict__ aW,
    const float* __restrict__ gnw, const float* __restrict__ gnb,
    const float* __restrict__ MU, const float* __restrict__ RSTD,
    const float* __restrict__ V2, const float* __restrict__ Z2,
    const float* __restrict__ V3, const float* __restrict__ Z3,
    float* __restrict__ out)
{
  __shared__ __align__(16) float ahs[1024], aws[1024];
  __shared__ float sc_s[16], of_s[16], p2s[16], p3s[16], red[16];
  __shared__ float invS_s;
  int tid = threadIdx.x, bg = blockIdx.x;
  const float4* x4 = (const float4*)x + (size_t)bg * CHW4;
  const ushort4* X34 = (const ushort4*)X3 + (size_t)bg * CHW4;
  float4* o4 = (float4*)out + (size_t)bg * CHW4;
  ahs[tid] = aH[(size_t)bg*1024 + tid];
  aws[tid] = aW[(size_t)bg*1024 + tid];
  if (tid < 16){
    float mu = MU[bg], rstd = RSTD[bg];
    float g = gnw[tid], b = gnb[tid];
    float sc = rstd*g;
    sc_s[tid] = sc; of_s[tid] = b - mu*sc;
    p2s[tid] = V3[(size_t)bg*16+tid] * (1.f/4096.f) / Z2[(size_t)bg*16+tid];
    p3s[tid] = V2[(size_t)bg*16+tid] / Z3[(size_t)bg*16+tid];
  }
  __syncthreads();
  int h = tid >> 4, w4 = tid & 15, lane = tid & 63, wv = tid >> 6;
  const float4* aws4 = (const float4*)aws;
  float4 tacc = make_float4(0.f,0.f,0.f,0.f);
#pragma unroll 2
  for (int k = 0; k < 16; ++k){
    float4 v = x4[k*1024 + tid];
    ushort4 xu = X34[k*1024 + tid];
    float ah = ahs[k*64 + h];
    float4 aw = aws4[k*16 + w4];
    float sc = sc_s[k], of = of_s[k], p2 = p2s[k], p3 = p3s[k];
    tacc.x += __expf(fmaf(v.x*ah*aw.x, sc, of))*p2 + __expf(bf2f(xu.x))*p3;
    tacc.y += __expf(fmaf(v.y*ah*aw.y, sc, of))*p2 + __expf(bf2f(xu.y))*p3;
    tacc.z += __expf(fmaf(v.z*ah*aw.z, sc, of))*p2 + __expf(bf2f(xu.z))*p3;
    tacc.w += __expf(fmaf(v.w*ah*aw.w, sc, of))*p2 + __expf(bf2f(xu.w))*p3;
  }
  float4 e;
  e.x = __expf(tacc.x); e.y = __expf(tacc.y);
  e.z = __expf(tacc.z); e.w = __expf(tacc.w);
  float es = e.x + e.y + e.z + e.w;
  float r = wred(es);
  if (lane == 0) red[wv] = r;
  __syncthreads();
  if (tid == 0){
    float S = 0.f;
#pragma unroll
    for (int i = 0; i < 16; ++i) S += red[i];
    invS_s = 1.f / S;
  }
  __syncthreads();
  float iS = invS_s;
  float4 ei = make_float4(e.x*iS, e.y*iS, e.z*iS, e.w*iS);
#pragma unroll 4
  for (int k = 0; k < 16; ++k){
    float4 v = x4[k*1024 + tid];
    float4 ov;
    ov.x = v.x * ei.x; ov.y = v.y * ei.y;
    ov.z = v.z * ei.z; ov.w = v.w * ei.w;
    o4[k*1024 + tid] = ov;
  }
}

extern "C" void kernel_launch(void* const* d_in, const int* in_sizes, int n_in,
                              void* d_out, int out_size, void* d_ws, size_t ws_size,
                              hipStream_t stream)
{
  const float* x   = (const float*)d_in[0];
  const float* w1  = (const float*)d_in[1];
  const float* b1  = (const float*)d_in[2];
  const float* wh  = (const float*)d_in[3];
  const float* bh  = (const float*)d_in[4];
  const float* ww  = (const float*)d_in[5];
  const float* bw  = (const float*)d_in[6];
  const float* w3  = (const float*)d_in[7];
  const float* b3  = (const float*)d_in[8];
  const float* gnw = (const float*)d_in[9];
  const float* gnb = (const float*)d_in[10];
  float* out = (float*)d_out;

  float* Wp   = (float*)d_ws;
  float* aH   = Wp;                 // 512*16*64
  float* aW_  = aH + 524288;        // 512*16*64
  float* MU   = aW_ + 524288;       // 512
  float* RSTD = MU + 512;           // 512
  float* V2   = RSTD + 512;         // 8192
  float* Z2   = V2 + 8192;          // 8192
  float* V3   = Z2 + 8192;          // 8192 (raw sums, atomically accumulated)
  float* Z3   = V3 + 8192;          // 8192 (raw sums)
  __hip_bfloat16* X3 = (__hip_bfloat16*)(Z3 + 8192);  // 33554432 bf16 (64 MB)
  (void)ws_size; (void)n_in; (void)in_sizes; (void)out_size;

  hipMemsetAsync(V3, 0, 2 * 8192 * sizeof(float), stream);
  k1_attn <<<512, 1024, 0, stream>>>(x, w1, b1, wh, bh, ww, bw, aH, aW_);
  k3_conv <<<dim3(8, 512), 256, 0, stream>>>(x, w3, b3, X3, V3, Z3);
  k2_stats<<<512, 1024, 0, stream>>>(x, aH, aW_, gnw, gnb, MU, RSTD, V2, Z2);
  k4_final<<<512, 1024, 0, stream>>>(x, X3, aH, aW_, gnw, gnb, MU, RSTD, V2, Z2, V3, Z3, out);
}

// Round 3
// 476.809 us; speedup vs baseline: 1.9933x; 1.0751x over previous
//
#include <hip/hip_runtime.h>
#include <hip/hip_bf16.h>

#define CHW  65536   // 16 ch * 64 * 64 per bg-group
#define CHW4 16384   // in float4

__device__ __forceinline__ float wred(float v){
#pragma unroll
  for (int o = 32; o; o >>= 1) v += __shfl_xor(v, o, 64);
  return v;
}
__device__ __forceinline__ float wred16(float v){
#pragma unroll
  for (int o = 8; o; o >>= 1) v += __shfl_xor(v, o, 64);
  return v;
}
__device__ __forceinline__ float bf2f(unsigned short u){
  return __uint_as_float(((unsigned)u) << 16);
}

// ---------------- K3: 3x3 grouped conv -> E3=exp(x3) (bf16), V3/Z3 stripe partials ----
// Grid (8 stripes, 512 groups), 256 threads. Split-ci staging: 8 ci per round,
// LDS 8*10*84*4 = 26.9 KB -> 6 blocks/CU.
#define STR 84
__global__ __launch_bounds__(256, 6) void k3_conv(const float* __restrict__ x,
    const float* __restrict__ w3, const float* __restrict__ b3,
    __hip_bfloat16* __restrict__ E3,
    float* __restrict__ V3part, float* __restrict__ Z3part)
{
  __shared__ __align__(16) float in_s[8*10*STR];
  int tid = threadIdx.x;
  int s   = blockIdx.x;      // stripe 0..7
  int bg  = blockIdx.y;
  size_t base  = (size_t)bg * CHW;
  const float4* x4 = (const float4*)x + (size_t)bg * CHW4;
  int lane = tid & 63;
  int cog = __builtin_amdgcn_readfirstlane(tid >> 6);  // wave-uniform co group
  int co0 = cog * 4;
  int r  = lane >> 3;          // output row within stripe
  int w0 = (lane & 7) * 8;     // 8 consecutive output cols
  float acc[4][8];
#pragma unroll
  for (int i = 0; i < 4; ++i)
#pragma unroll
    for (int px = 0; px < 8; ++px) acc[i][px] = 0.f;

#pragma unroll 1
  for (int half = 0; half < 2; ++half){
    __syncthreads();
    // stage 8 ci x 10 rows x 72 cols (cols -4..67 zero-padded)
    for (int idx = tid; idx < 1440; idx += 256){
      int q   = idx % 18;
      int rr  = (idx / 18) % 10;
      int ci8 = idx / 180;
      int hh  = s*8 - 1 + rr;
      float4 v = make_float4(0.f, 0.f, 0.f, 0.f);
      if (q >= 1 && q <= 16 && (unsigned)hh < 64u)
        v = x4[(half*8 + ci8)*1024 + hh*16 + (q-1)];
      *(float4*)&in_s[(ci8*10 + rr)*STR + q*4] = v;
    }
    __syncthreads();
#pragma unroll 1
    for (int ci8 = 0; ci8 < 8; ++ci8){
      int ci = half*8 + ci8;
      float wgt[4][9];
#pragma unroll
      for (int i = 0; i < 4; ++i)
#pragma unroll
        for (int t = 0; t < 9; ++t)
          wgt[i][t] = w3[((co0+i)*16 + ci)*9 + t];   // wave-uniform -> scalar loads
#pragma unroll
      for (int dy = 0; dy < 3; ++dy){
        const float* row = &in_s[(ci8*10 + r + dy)*STR + w0];
        float4 A0 = *(const float4*)(row);
        float4 A1 = *(const float4*)(row+4);
        float4 A2v = *(const float4*)(row+8);
        float4 A3v = *(const float4*)(row+12);
        float v[16] = {A0.x,A0.y,A0.z,A0.w, A1.x,A1.y,A1.z,A1.w,
                       A2v.x,A2v.y,A2v.z,A2v.w, A3v.x,A3v.y,A3v.z,A3v.w};
#pragma unroll
        for (int dx = 0; dx < 3; ++dx){
#pragma unroll
          for (int px = 0; px < 8; ++px){
            float iv = v[px + dx + 3];
#pragma unroll
            for (int i = 0; i < 4; ++i)
              acc[i][px] = fmaf(wgt[i][dy*3+dx], iv, acc[i][px]);
          }
        }
      }
    }
  }
  int hh = s*8 + r;
#pragma unroll
  for (int i = 0; i < 4; ++i){
    float bias = b3[co0+i];
    union { __hip_bfloat16 hb[8]; uint4 u; } pk;
    float v3acc = 0.f, z3acc = 0.f;
#pragma unroll
    for (int px = 0; px < 8; ++px){
      float val = fmaxf(acc[i][px] + bias, 0.f);   // x3
      float e = __expf(val);
      v3acc += val;
      z3acc += e;
      pk.hb[px] = __float2bfloat16(e);
    }
    *(uint4*)&E3[base + (size_t)(co0+i)*4096 + hh*64 + w0] = pk.u;
    float rv = wred(v3acc);
    float rz = wred(z3acc);
    if (lane == 0){
      V3part[((size_t)bg*8 + s)*16 + co0 + i] = rv;
      Z3part[((size_t)bg*8 + s)*16 + co0 + i] = rz;
    }
  }
}

// ---------------- MEGA: k1 (a_h/a_w) + k2 (stats) + k4 (t, softmax, out) ------------
// One 1024-thread block per bg-group; all attention/stat state stays in LDS.
__global__ __launch_bounds__(1024, 8) void mega(const float* __restrict__ x,
    const float* __restrict__ w1, const float* __restrict__ b1,
    const float* __restrict__ wh, const float* __restrict__ bh,
    const float* __restrict__ ww, const float* __restrict__ bw,
    const float* __restrict__ gnw, const float* __restrict__ gnb,
    const float* __restrict__ V3part, const float* __restrict__ Z3part,
    const __hip_bfloat16* __restrict__ E3,
    float* __restrict__ out)
{
  __shared__ float rs[1024];                 // rowsum[ch*64+h]
  __shared__ float cs[1024];                 // colsum[ch*64+w]
  __shared__ float ym[2048];
  __shared__ __align__(16) float ahs[1024], aws[1024];
  __shared__ float chpart[256], zpart[256];
  __shared__ float red1[16], red2[16];
  __shared__ float murs[2];
  __shared__ float sc_s[16], of_s[16], v2_s[16], p2s[16], p3s[16];
  __shared__ float invS_s;

  int tid = threadIdx.x, bg = blockIdx.x;
  const float4* x4 = (const float4*)x + (size_t)bg * CHW4;
  const ushort4* E34 = (const ushort4*)E3 + (size_t)bg * CHW4;
  float4* o4 = (float4*)out + (size_t)bg * CHW4;
  int h = tid >> 4, w4 = tid & 15, lane = tid & 63, wv = tid >> 6;

  // ---- pass 0: pooled row/col sums ----
  cs[tid] = 0.f;
  __syncthreads();
#pragma unroll 4
  for (int k = 0; k < 16; ++k){          // k == channel
    float4 v = x4[k*1024 + tid];
    float srow = v.x + v.y + v.z + v.w;
    srow = wred16(srow);
    if ((tid & 15) == 0) rs[k*64 + h] = srow;
    v.x += __shfl_xor(v.x, 16); v.x += __shfl_xor(v.x, 32);
    v.y += __shfl_xor(v.y, 16); v.y += __shfl_xor(v.y, 32);
    v.z += __shfl_xor(v.z, 16); v.z += __shfl_xor(v.z, 32);
    v.w += __shfl_xor(v.w, 16); v.w += __shfl_xor(v.w, 32);
    if (lane < 16){
      atomicAdd(&cs[k*64 + lane*4 + 0], v.x);
      atomicAdd(&cs[k*64 + lane*4 + 1], v.y);
      atomicAdd(&cs[k*64 + lane*4 + 2], v.z);
      atomicAdd(&cs[k*64 + lane*4 + 3], v.w);
    }
  }
  __syncthreads();
  // y = relu(w1 @ [rowmean|colmean] + b1)
  for (int ol = tid; ol < 2048; ol += 1024){
    int o = ol >> 7, l = ol & 127;
    float acc = b1[o];
#pragma unroll
    for (int i = 0; i < 16; ++i){
      float mv = (l < 64 ? rs[i*64 + l] : cs[i*64 + (l-64)]) * (1.f/64.f);
      acc = fmaf(w1[o*16 + i], mv, acc);
    }
    ym[o*128 + l] = fmaxf(acc, 0.f);
  }
  __syncthreads();
  for (int ol = tid; ol < 2048; ol += 1024){
    int q = ol >> 10;             // 0 -> a_h, 1 -> a_w
    int o = (ol >> 6) & 15;
    int p = ol & 63;
    const float* Wm = q ? ww : wh;
    float acc = q ? bw[o] : bh[o];
#pragma unroll
    for (int i = 0; i < 16; ++i)
      acc = fmaf(Wm[o*16 + i], ym[i*128 + q*64 + p], acc);
    float sg = 1.f / (1.f + __expf(-acc));
    (q ? aws : ahs)[o*64 + p] = sg;
  }
  __syncthreads();

  // ---- pass A: mu/var + per-channel sums ----
  const float4* aws4 = (const float4*)aws;
  float s1 = 0.f, s2 = 0.f;
#pragma unroll 4
  for (int k = 0; k < 16; ++k){
    float4 v = x4[k*1024 + tid];
    float ah = ahs[k*64 + h];
    float4 aw = aws4[k*16 + w4];
    float4 x1;
    x1.x = v.x * ah * aw.x;
    x1.y = v.y * ah * aw.y;
    x1.z = v.z * ah * aw.z;
    x1.w = v.w * ah * aw.w;
    float csum = x1.x + x1.y + x1.z + x1.w;
    s1 += csum;
    s2 = fmaf(x1.x, x1.x, s2); s2 = fmaf(x1.y, x1.y, s2);
    s2 = fmaf(x1.z, x1.z, s2); s2 = fmaf(x1.w, x1.w, s2);
    float cw = wred(csum);
    if (lane == 0) chpart[k*16 + wv] = cw;
  }
  float r1 = wred(s1), r2 = wred(s2);
  if (lane == 0){ red1[wv] = r1; red2[wv] = r2; }
  __syncthreads();
  if (tid == 0){
    float S = 0.f, SS = 0.f;
#pragma unroll
    for (int i = 0; i < 16; ++i){ S += red1[i]; SS += red2[i]; }
    float mu = S * (1.f/65536.f);
    float var = SS * (1.f/65536.f) - mu*mu;
    murs[0] = mu; murs[1] = rsqrtf(var + 1e-5f);
  }
  __syncthreads();
  if (tid < 16){
    float ch = 0.f;
#pragma unroll
    for (int m = 0; m < 16; ++m) ch += chpart[tid*16 + m];
    float mu = murs[0], rstd = murs[1];
    float g = gnw[tid], b = gnb[tid];
    float sc = rstd * g;
    sc_s[tid] = sc; of_s[tid] = b - mu*sc;
    v2_s[tid] = (ch * (1.f/4096.f) - mu) * sc + b;   // V2
  }
  __syncthreads();

  // ---- pass B: Z2 per channel ----
#pragma unroll 2
  for (int k = 0; k < 16; ++k){
    float4 v = x4[k*1024 + tid];
    float ah = ahs[k*64 + h];
    float4 aw = aws4[k*16 + w4];
    float sc = sc_s[k], of = of_s[k];
    float z =  __expf(fmaf(v.x * ah * aw.x, sc, of));
    z += __expf(fmaf(v.y * ah * aw.y, sc, of));
    z += __expf(fmaf(v.z * ah * aw.z, sc, of));
    z += __expf(fmaf(v.w * ah * aw.w, sc, of));
    float zw = wred(z);
    if (lane == 0) zpart[k*16 + wv] = zw;
  }
  __syncthreads();
  if (tid < 16){
    float z2 = 0.f;
#pragma unroll
    for (int m = 0; m < 16; ++m) z2 += zpart[tid*16 + m];
    float v3 = 0.f, z3 = 0.f;
#pragma unroll
    for (int ss = 0; ss < 8; ++ss){
      v3 += V3part[((size_t)bg*8 + ss)*16 + tid];
      z3 += Z3part[((size_t)bg*8 + ss)*16 + tid];
    }
    p2s[tid] = v3 * (1.f/4096.f) / z2;   // multiplies exp(x2):  V3 * A2
    p3s[tid] = v2_s[tid] / z3;           // multiplies exp(x3):  V2 * A3
  }
  __syncthreads();

  // ---- pass C: t accumulation (register-private, 4 px/thread) ----
  float4 tacc = make_float4(0.f,0.f,0.f,0.f);
#pragma unroll 2
  for (int k = 0; k < 16; ++k){
    float4 v = x4[k*1024 + tid];
    ushort4 eu = E34[k*1024 + tid];
    float ah = ahs[k*64 + h];
    float4 aw = aws4[k*16 + w4];
    float sc = sc_s[k], of = of_s[k], p2 = p2s[k], p3 = p3s[k];
    tacc.x += __expf(fmaf(v.x*ah*aw.x, sc, of))*p2 + bf2f(eu.x)*p3;
    tacc.y += __expf(fmaf(v.y*ah*aw.y, sc, of))*p2 + bf2f(eu.y)*p3;
    tacc.z += __expf(fmaf(v.z*ah*aw.z, sc, of))*p2 + bf2f(eu.z)*p3;
    tacc.w += __expf(fmaf(v.w*ah*aw.w, sc, of))*p2 + bf2f(eu.w)*p3;
  }
  float4 e;
  e.x = __expf(tacc.x); e.y = __expf(tacc.y);
  e.z = __expf(tacc.z); e.w = __expf(tacc.w);
  float es = e.x + e.y + e.z + e.w;
  float rr = wred(es);
  if (lane == 0) red1[wv] = rr;
  __syncthreads();
  if (tid == 0){
    float S = 0.f;
#pragma unroll
    for (int i = 0; i < 16; ++i) S += red1[i];
    invS_s = 1.f / S;
  }
  __syncthreads();
  float iS = invS_s;
  float4 ei = make_float4(e.x*iS, e.y*iS, e.z*iS, e.w*iS);

  // ---- pass D: out = x * s ----
#pragma unroll 4
  for (int k = 0; k < 16; ++k){
    float4 v = x4[k*1024 + tid];
    float4 ov;
    ov.x = v.x * ei.x; ov.y = v.y * ei.y;
    ov.z = v.z * ei.z; ov.w = v.w * ei.w;
    o4[k*1024 + tid] = ov;
  }
}

extern "C" void kernel_launch(void* const* d_in, const int* in_sizes, int n_in,
                              void* d_out, int out_size, void* d_ws, size_t ws_size,
                              hipStream_t stream)
{
  const float* x   = (const float*)d_in[0];
  const float* w1  = (const float*)d_in[1];
  const float* b1  = (const float*)d_in[2];
  const float* wh  = (const float*)d_in[3];
  const float* bh  = (const float*)d_in[4];
  const float* ww  = (const float*)d_in[5];
  const float* bw  = (const float*)d_in[6];
  const float* w3  = (const float*)d_in[7];
  const float* b3  = (const float*)d_in[8];
  const float* gnw = (const float*)d_in[9];
  const float* gnb = (const float*)d_in[10];
  float* out = (float*)d_out;

  float* V3part = (float*)d_ws;                       // 512*8*16 = 65536 floats
  float* Z3part = V3part + 65536;                     // 65536 floats
  __hip_bfloat16* E3 = (__hip_bfloat16*)(Z3part + 65536);  // 33554432 bf16 (64 MB)
  (void)ws_size; (void)n_in; (void)in_sizes; (void)out_size;

  k3_conv<<<dim3(8, 512), 256, 0, stream>>>(x, w3, b3, E3, V3part, Z3part);
  mega   <<<512, 1024, 0, stream>>>(x, w1, b1, wh, bh, ww, bw, gnw, gnb,
                                    V3part, Z3part, E3, out);
}